// Round 3
// baseline (248.370 us; speedup 1.0000x reference)
//
#include <hip/hip_runtime.h>

typedef unsigned int uint32;
typedef __attribute__((ext_vector_type(8))) short short8v;  // 8 bf16 (4 VGPRs)
typedef __attribute__((ext_vector_type(4))) float f32x4;

__device__ __forceinline__ unsigned short f2bf(float f) {
  unsigned u = __float_as_uint(f);
  return (unsigned short)((u + 0x7FFFu + ((u >> 16) & 1u)) >> 16);
}
__device__ __forceinline__ float bfl(unsigned x) { return __uint_as_float(x << 16); }
__device__ __forceinline__ float bfh(unsigned x) { return __uint_as_float(x & 0xFFFF0000u); }

// k0: zero the 1024-elem output + detect edge_mask element size (1B bool vs 4B).
__global__ __launch_bounds__(256) void k0_detect_zero(const uint32* __restrict__ md,
                                                      int* __restrict__ flag,
                                                      float* __restrict__ out) {
  int t = blockIdx.x * blockDim.x + threadIdx.x;
  if (t < 1024) out[t] = 0.f;
  if (blockIdx.x == 0 && threadIdx.x < 64) {
    bool ok4 = true;
    for (int i = threadIdx.x; i < 1024; i += 64) {
      uint32 v = md[i];
      if (!(v == 0u || v == 1u || v == 0x3F800000u)) ok4 = false;
    }
    bool all4 = __all(ok4);
    if (threadIdx.x == 0) *flag = all4 ? 4 : 1;
  }
}

// k1: Wh = X @ W1 via mfma_f32_16x16x32_bf16 (unchanged from R2; ~20us).
__global__ __launch_bounds__(256) void k1_mfma(const float* __restrict__ X,
                                               const float* __restrict__ W,
                                               unsigned short* __restrict__ Wh,
                                               int N) {
  __shared__ short sB[2048 * 8];  // 32 KiB
  const int tid = threadIdx.x;
  for (int i = tid; i < 2048; i += 256) {
    const int frag = i >> 6, ln = i & 63;
    const int kt = frag >> 3, ct = frag & 7, p = ln >> 4, q = ln & 15;
    short8v v;
    #pragma unroll
    for (int j = 0; j < 8; ++j)
      v[j] = (short)f2bf(W[(kt * 32 + p * 8 + j) * 128 + ct * 16 + q]);
    *(short8v*)&sB[i * 8] = v;
  }
  __syncthreads();

  const int lane = tid & 63;
  const int p = lane >> 4, q = lane & 15;
  const int wave = blockIdx.x * 4 + (tid >> 6);
  const int nwaves = gridDim.x * 4;
  const int nstrips = (N + 15) >> 4;

  for (int s = wave; s < nstrips; s += nwaves) {
    const int row = s * 16 + q;
    const int rclamp = row < N ? row : (N - 1);
    const float* xr = X + (size_t)rclamp * 128 + p * 8;
    float4 L[8];
    #pragma unroll
    for (int kt = 0; kt < 4; ++kt) {
      L[2 * kt]     = *(const float4*)(xr + kt * 32);
      L[2 * kt + 1] = *(const float4*)(xr + kt * 32 + 4);
    }
    short8v A[4];
    #pragma unroll
    for (int kt = 0; kt < 4; ++kt) {
      #pragma unroll
      for (int j = 0; j < 4; ++j) {
        A[kt][j]     = (short)f2bf((&L[2 * kt].x)[j]);
        A[kt][j + 4] = (short)f2bf((&L[2 * kt + 1].x)[j]);
      }
    }
    f32x4 acc[8];
    #pragma unroll
    for (int ct = 0; ct < 8; ++ct) acc[ct] = (f32x4){0.f, 0.f, 0.f, 0.f};
    #pragma unroll
    for (int kt = 0; kt < 4; ++kt) {
      #pragma unroll
      for (int ct = 0; ct < 8; ++ct) {
        short8v b = *(const short8v*)&sB[((kt * 8 + ct) * 64 + lane) * 8];
        acc[ct] = __builtin_amdgcn_mfma_f32_16x16x32_bf16(A[kt], b, acc[ct], 0, 0, 0);
      }
    }
    const int r0 = s * 16 + p * 4;
    #pragma unroll
    for (int ct = 0; ct < 8; ++ct) {
      #pragma unroll
      for (int r = 0; r < 4; ++r) {
        const int rr = r0 + r;
        if (rr < N) Wh[(size_t)rr * 128 + ct * 16 + q] = f2bf(acc[ct][r]);
      }
    }
  }
}

// k2 body, templated on mask element size. 4 waves/block, 4 edges/wave/iter.
// Lane = (g,t): group g owns arity slot g, lane t owns cols [t*16, t*16+16).
// Batched loads: 4x idx+mask, then 8x dwordx4 gathers, then 4 independent
// shfl-reduce softmax chains. Branchless: invalid slots get att=0.
template <int MSZ>
__device__ __forceinline__ void k2_body(const unsigned short* __restrict__ Wh,
                                        const int* __restrict__ elist,
                                        const void* __restrict__ maskp,
                                        const float* __restrict__ a1,
                                        float* __restrict__ out, int M,
                                        float (&sAcc)[4][1024]) {
  const int lane = threadIdx.x & 63;
  const int wv = threadIdx.x >> 6;      // 0..3
  const int g = lane >> 3, t = lane & 7;

  float a1r[16];
  #pragma unroll
  for (int j = 0; j < 16; j += 4) {
    float4 v = *(const float4*)&a1[t * 16 + j];
    a1r[j] = v.x; a1r[j + 1] = v.y; a1r[j + 2] = v.z; a1r[j + 3] = v.w;
  }
  float acc[16];
  #pragma unroll
  for (int j = 0; j < 16; ++j) acc[j] = 0.f;

  const int gw = blockIdx.x * 4 + wv;
  const int nw = gridDim.x * 4;
  for (int base = gw * 4; base < M; base += nw * 4) {
    int idx[4], vld[4];
    #pragma unroll
    for (int ed = 0; ed < 4; ++ed) {
      const int m = base + ed;
      const bool in = m < M;
      const int e = in ? m * 8 + g : g;
      idx[ed] = elist[e];
      if (MSZ == 4) vld[ed] = in ? ((const int*)maskp)[e] : 0;
      else          vld[ed] = in ? (int)((const unsigned char*)maskp)[e] : 0;
    }
    uint4 u0[4], u1[4];
    #pragma unroll
    for (int ed = 0; ed < 4; ++ed) {
      const uint4* p = (const uint4*)(Wh + (size_t)idx[ed] * 128 + t * 16);
      u0[ed] = p[0];
      u1[ed] = p[1];
    }
    float part[4];
    #pragma unroll
    for (int ed = 0; ed < 4; ++ed) {
      const unsigned d[8] = {u0[ed].x, u0[ed].y, u0[ed].z, u0[ed].w,
                             u1[ed].x, u1[ed].y, u1[ed].z, u1[ed].w};
      float s = 0.f;
      #pragma unroll
      for (int jj = 0; jj < 8; ++jj) {
        const float lo = bfl(d[jj]), hi = bfh(d[jj]);
        s += fmaxf(lo, 0.2f * lo) * a1r[2 * jj];
        s += fmaxf(hi, 0.2f * hi) * a1r[2 * jj + 1];
      }
      part[ed] = s;
    }
    // group reduce (4 independent chains; compiler interleaves)
    #pragma unroll
    for (int ed = 0; ed < 4; ++ed) {
      part[ed] += __shfl_xor(part[ed], 1);
      part[ed] += __shfl_xor(part[ed], 2);
      part[ed] += __shfl_xor(part[ed], 4);
    }
    float att[4];
    #pragma unroll
    for (int ed = 0; ed < 4; ++ed) {
      const float s = vld[ed] ? part[ed] : -9e15f;
      float mx = s;
      mx = fmaxf(mx, __shfl_xor(mx, 8));
      mx = fmaxf(mx, __shfl_xor(mx, 16));
      mx = fmaxf(mx, __shfl_xor(mx, 32));
      const float ev = vld[ed] ? __expf(s - mx) : 0.f;
      float dn = ev;
      dn += __shfl_xor(dn, 8);
      dn += __shfl_xor(dn, 16);
      dn += __shfl_xor(dn, 32);
      att[ed] = vld[ed] ? __fdividef(ev, dn) : 0.f;
    }
    #pragma unroll
    for (int ed = 0; ed < 4; ++ed) {
      const unsigned d[8] = {u0[ed].x, u0[ed].y, u0[ed].z, u0[ed].w,
                             u1[ed].x, u1[ed].y, u1[ed].z, u1[ed].w};
      const float a = att[ed];
      #pragma unroll
      for (int jj = 0; jj < 8; ++jj) {
        acc[2 * jj]     = fmaf(a, bfl(d[jj]), acc[2 * jj]);
        acc[2 * jj + 1] = fmaf(a, bfh(d[jj]), acc[2 * jj + 1]);
      }
    }
  }

  #pragma unroll
  for (int j = 0; j < 16; ++j) sAcc[wv][g * 128 + t * 16 + j] = acc[j];
  __syncthreads();
  const int c = threadIdx.x * 4;
  float4 s = {0.f, 0.f, 0.f, 0.f};
  #pragma unroll
  for (int w = 0; w < 4; ++w) {
    float4 v = *(const float4*)&sAcc[w][c];
    s.x += v.x; s.y += v.y; s.z += v.z; s.w += v.w;
  }
  atomicAdd(&out[c], s.x);
  atomicAdd(&out[c + 1], s.y);
  atomicAdd(&out[c + 2], s.z);
  atomicAdd(&out[c + 3], s.w);
}

__global__ __launch_bounds__(256) void k2_edges(const unsigned short* __restrict__ Wh,
                                                const int* __restrict__ elist,
                                                const void* __restrict__ maskp,
                                                const float* __restrict__ a1,
                                                const int* __restrict__ flag,
                                                float* __restrict__ out, int M) {
  __shared__ float sAcc[4][1024];
  if (*flag == 4) k2_body<4>(Wh, elist, maskp, a1, out, M, sAcc);
  else            k2_body<1>(Wh, elist, maskp, a1, out, M, sAcc);
}

extern "C" void kernel_launch(void* const* d_in, const int* in_sizes, int n_in,
                              void* d_out, int out_size, void* d_ws, size_t ws_size,
                              hipStream_t stream) {
  const float* node          = (const float*)d_in[0];
  const int* elist           = (const int*)d_in[2];
  const void* maskp          = (const void*)d_in[3];
  const float* W1            = (const float*)d_in[4];
  const float* a1            = (const float*)d_in[5];
  float* out                 = (float*)d_out;

  const int N = in_sizes[0] / 128;
  const int M = in_sizes[2] / 8;

  unsigned short* Wh = (unsigned short*)d_ws;           // bf16 Wh, N*128*2 bytes
  const size_t whBytes = (size_t)N * 128 * 2;
  int* flag = (int*)((char*)d_ws + whBytes);

  k0_detect_zero<<<4, 256, 0, stream>>>((const uint32*)maskp, flag, out);
  k1_mfma<<<784, 256, 0, stream>>>(node, W1, Wh, N);
  k2_edges<<<2048, 256, 0, stream>>>((const unsigned short*)Wh, elist, maskp, a1, flag, out, M);
}

// Round 4
// 117.304 us; speedup vs baseline: 2.1173x; 2.1173x over previous
//
#include <hip/hip_runtime.h>

typedef unsigned int uint32;
typedef __attribute__((ext_vector_type(8))) short short8v;  // 8 bf16 (4 VGPRs)
typedef __attribute__((ext_vector_type(4))) float f32x4;

__device__ __forceinline__ unsigned short f2bf(float f) {
  unsigned u = __float_as_uint(f);
  return (unsigned short)((u + 0x7FFFu + ((u >> 16) & 1u)) >> 16);
}
__device__ __forceinline__ float bfl(unsigned x) { return __uint_as_float(x << 16); }
__device__ __forceinline__ float bfh(unsigned x) { return __uint_as_float(x & 0xFFFF0000u); }

// k0: zero W8 table + detect edge_mask element size (1B bool vs 4B int/float).
__global__ __launch_bounds__(256) void k0_zero_detect(const uint32* __restrict__ md,
                                                      int* __restrict__ flag,
                                                      float4* __restrict__ W8v, int n4) {
  const int t = blockIdx.x * blockDim.x + threadIdx.x;
  for (int i = t; i < n4; i += gridDim.x * blockDim.x)
    W8v[i] = (float4){0.f, 0.f, 0.f, 0.f};
  if (blockIdx.x == 0 && threadIdx.x < 64) {
    bool ok4 = true;
    for (int i = threadIdx.x; i < 1024; i += 64) {
      uint32 v = md[i];
      if (!(v == 0u || v == 1u || v == 0x3F800000u)) ok4 = false;
    }
    bool all4 = __all(ok4);
    if (threadIdx.x == 0) *flag = all4 ? 4 : 1;
  }
}

// k1: Wh = X @ W1 via mfma_f32_16x16x32_bf16 (R2 structure) + fused sigma
// epilogue: sigma[n] = sum_f lrelu(Wh[n][f]) * a1[f], computed from fp32 acc.
// C/D layout: col = lane&15 (q), row = (lane>>4)*4 + reg (p*4+r).
__global__ __launch_bounds__(256) void k1_mfma(const float* __restrict__ X,
                                               const float* __restrict__ W,
                                               const float* __restrict__ a1,
                                               unsigned short* __restrict__ Wh,
                                               float* __restrict__ sigma,
                                               int N) {
  __shared__ short sB[2048 * 8];  // 32 KiB
  const int tid = threadIdx.x;
  for (int i = tid; i < 2048; i += 256) {
    const int frag = i >> 6, ln = i & 63;
    const int kt = frag >> 3, ct = frag & 7, p = ln >> 4, q = ln & 15;
    short8v v;
    #pragma unroll
    for (int j = 0; j < 8; ++j)
      v[j] = (short)f2bf(W[(kt * 32 + p * 8 + j) * 128 + ct * 16 + q]);
    *(short8v*)&sB[i * 8] = v;
  }
  __syncthreads();

  const int lane = tid & 63;
  const int p = lane >> 4, q = lane & 15;
  float a1v[8];
  #pragma unroll
  for (int ct = 0; ct < 8; ++ct) a1v[ct] = a1[ct * 16 + q];

  const int wave = blockIdx.x * 4 + (tid >> 6);
  const int nwaves = gridDim.x * 4;
  const int nstrips = (N + 15) >> 4;

  for (int s = wave; s < nstrips; s += nwaves) {
    const int row = s * 16 + q;
    const int rclamp = row < N ? row : (N - 1);
    const float* xr = X + (size_t)rclamp * 128 + p * 8;
    float4 L[8];
    #pragma unroll
    for (int kt = 0; kt < 4; ++kt) {
      L[2 * kt]     = *(const float4*)(xr + kt * 32);
      L[2 * kt + 1] = *(const float4*)(xr + kt * 32 + 4);
    }
    short8v A[4];
    #pragma unroll
    for (int kt = 0; kt < 4; ++kt) {
      #pragma unroll
      for (int j = 0; j < 4; ++j) {
        A[kt][j]     = (short)f2bf((&L[2 * kt].x)[j]);
        A[kt][j + 4] = (short)f2bf((&L[2 * kt + 1].x)[j]);
      }
    }
    f32x4 acc[8];
    #pragma unroll
    for (int ct = 0; ct < 8; ++ct) acc[ct] = (f32x4){0.f, 0.f, 0.f, 0.f};
    #pragma unroll
    for (int kt = 0; kt < 4; ++kt) {
      #pragma unroll
      for (int ct = 0; ct < 8; ++ct) {
        short8v b = *(const short8v*)&sB[((kt * 8 + ct) * 64 + lane) * 8];
        acc[ct] = __builtin_amdgcn_mfma_f32_16x16x32_bf16(A[kt], b, acc[ct], 0, 0, 0);
      }
    }
    const int r0 = s * 16 + p * 4;
    #pragma unroll
    for (int ct = 0; ct < 8; ++ct) {
      #pragma unroll
      for (int r = 0; r < 4; ++r) {
        const int rr = r0 + r;
        if (rr < N) Wh[(size_t)rr * 128 + ct * 16 + q] = f2bf(acc[ct][r]);
      }
    }
    // sigma epilogue: row-sum of lrelu(acc)*a1 over 128 cols
    #pragma unroll
    for (int r = 0; r < 4; ++r) {
      float tsum = 0.f;
      #pragma unroll
      for (int ct = 0; ct < 8; ++ct) {
        const float v = acc[ct][r];
        tsum += fmaxf(v, 0.2f * v) * a1v[ct];
      }
      tsum += __shfl_xor(tsum, 1);
      tsum += __shfl_xor(tsum, 2);
      tsum += __shfl_xor(tsum, 4);
      tsum += __shfl_xor(tsum, 8);
      const int rr = r0 + r;
      if (q == r && rr < N) sigma[rr] = tsum;
    }
  }
}

// k2a: one LANE per edge. Load 8 idx (coalesced 32B), 8 masks, gather 8 scalar
// sigmas (L2-resident 400KB table), in-lane softmax, atomicAdd att into W8[n][a].
template <int MSZ>
__device__ __forceinline__ void k2a_body(const int* __restrict__ elist,
                                         const void* __restrict__ maskp,
                                         const float* __restrict__ sigma,
                                         float* __restrict__ W8, int m) {
  const int4 ia = ((const int4*)elist)[m * 2];
  const int4 ib = ((const int4*)elist)[m * 2 + 1];
  const int idx[8] = {ia.x, ia.y, ia.z, ia.w, ib.x, ib.y, ib.z, ib.w};
  int vld[8];
  if (MSZ == 4) {
    const int4 ma = ((const int4*)maskp)[m * 2];
    const int4 mb = ((const int4*)maskp)[m * 2 + 1];
    vld[0] = ma.x; vld[1] = ma.y; vld[2] = ma.z; vld[3] = ma.w;
    vld[4] = mb.x; vld[5] = mb.y; vld[6] = mb.z; vld[7] = mb.w;
  } else {
    const uint2 u = ((const uint2*)maskp)[m];
    vld[0] = u.x & 0xFF; vld[1] = (u.x >> 8) & 0xFF;
    vld[2] = (u.x >> 16) & 0xFF; vld[3] = u.x >> 24;
    vld[4] = u.y & 0xFF; vld[5] = (u.y >> 8) & 0xFF;
    vld[6] = (u.y >> 16) & 0xFF; vld[7] = u.y >> 24;
  }
  float sg[8];
  #pragma unroll
  for (int a = 0; a < 8; ++a) sg[a] = sigma[idx[a]];
  float mx = -3.0e38f;
  #pragma unroll
  for (int a = 0; a < 8; ++a) mx = fmaxf(mx, vld[a] ? sg[a] : -3.0e38f);
  float ev[8];
  float dn = 0.f;
  #pragma unroll
  for (int a = 0; a < 8; ++a) {
    ev[a] = vld[a] ? __expf(sg[a] - mx) : 0.f;
    dn += ev[a];
  }
  const float inv = __fdividef(1.f, dn);
  #pragma unroll
  for (int a = 0; a < 8; ++a)
    if (vld[a]) atomicAdd(&W8[(size_t)idx[a] * 8 + a], ev[a] * inv);
}

__global__ __launch_bounds__(256) void k2a_edges(const int* __restrict__ elist,
                                                 const void* __restrict__ maskp,
                                                 const float* __restrict__ sigma,
                                                 const int* __restrict__ flag,
                                                 float* __restrict__ W8, int M) {
  const int m = blockIdx.x * 256 + threadIdx.x;
  if (m >= M) return;
  if (*flag == 4) k2a_body<4>(elist, maskp, sigma, W8, m);
  else            k2a_body<1>(elist, maskp, sigma, W8, m);
}

// k2b: out[a][f] = sum_n W8[n][a] * Wh[n][f]. Streaming, coalesced: lane holds
// cols {2*lane, 2*lane+1}; per node 1 dword Wh + 32B broadcast W8, 16 FMA.
// Block partial [8][128] -> plain store to partial[block][1024].
__global__ __launch_bounds__(256) void k2b_nodes(const uint32* __restrict__ Wh32,
                                                 const float* __restrict__ W8,
                                                 float* __restrict__ partial, int N) {
  __shared__ float sAcc[4][1024];
  const int lane = threadIdx.x & 63, wv = threadIdx.x >> 6;
  const int wave = blockIdx.x * 4 + wv, nw = gridDim.x * 4;
  float acc[16];
  #pragma unroll
  for (int j = 0; j < 16; ++j) acc[j] = 0.f;

  for (int n = wave; n < N; n += 2 * nw) {
    const int n2 = n + nw;
    const uint32 d0 = Wh32[(size_t)n * 64 + lane];
    const float4 wa0 = *(const float4*)&W8[(size_t)n * 8];
    const float4 wb0 = *(const float4*)&W8[(size_t)n * 8 + 4];
    uint32 d1 = 0;
    float4 wa1 = {0.f, 0.f, 0.f, 0.f}, wb1 = {0.f, 0.f, 0.f, 0.f};
    if (n2 < N) {
      d1 = Wh32[(size_t)n2 * 64 + lane];
      wa1 = *(const float4*)&W8[(size_t)n2 * 8];
      wb1 = *(const float4*)&W8[(size_t)n2 * 8 + 4];
    }
    const float lo0 = bfl(d0), hi0 = bfh(d0);
    acc[0]  = fmaf(wa0.x, lo0, acc[0]);  acc[1]  = fmaf(wa0.x, hi0, acc[1]);
    acc[2]  = fmaf(wa0.y, lo0, acc[2]);  acc[3]  = fmaf(wa0.y, hi0, acc[3]);
    acc[4]  = fmaf(wa0.z, lo0, acc[4]);  acc[5]  = fmaf(wa0.z, hi0, acc[5]);
    acc[6]  = fmaf(wa0.w, lo0, acc[6]);  acc[7]  = fmaf(wa0.w, hi0, acc[7]);
    acc[8]  = fmaf(wb0.x, lo0, acc[8]);  acc[9]  = fmaf(wb0.x, hi0, acc[9]);
    acc[10] = fmaf(wb0.y, lo0, acc[10]); acc[11] = fmaf(wb0.y, hi0, acc[11]);
    acc[12] = fmaf(wb0.z, lo0, acc[12]); acc[13] = fmaf(wb0.z, hi0, acc[13]);
    acc[14] = fmaf(wb0.w, lo0, acc[14]); acc[15] = fmaf(wb0.w, hi0, acc[15]);
    const float lo1 = bfl(d1), hi1 = bfh(d1);
    acc[0]  = fmaf(wa1.x, lo1, acc[0]);  acc[1]  = fmaf(wa1.x, hi1, acc[1]);
    acc[2]  = fmaf(wa1.y, lo1, acc[2]);  acc[3]  = fmaf(wa1.y, hi1, acc[3]);
    acc[4]  = fmaf(wa1.z, lo1, acc[4]);  acc[5]  = fmaf(wa1.z, hi1, acc[5]);
    acc[6]  = fmaf(wa1.w, lo1, acc[6]);  acc[7]  = fmaf(wa1.w, hi1, acc[7]);
    acc[8]  = fmaf(wb1.x, lo1, acc[8]);  acc[9]  = fmaf(wb1.x, hi1, acc[9]);
    acc[10] = fmaf(wb1.y, lo1, acc[10]); acc[11] = fmaf(wb1.y, hi1, acc[11]);
    acc[12] = fmaf(wb1.z, lo1, acc[12]); acc[13] = fmaf(wb1.z, hi1, acc[13]);
    acc[14] = fmaf(wb1.w, lo1, acc[14]); acc[15] = fmaf(wb1.w, hi1, acc[15]);
  }

  #pragma unroll
  for (int a = 0; a < 8; ++a) {
    sAcc[wv][a * 128 + 2 * lane]     = acc[2 * a];
    sAcc[wv][a * 128 + 2 * lane + 1] = acc[2 * a + 1];
  }
  __syncthreads();
  const int c = threadIdx.x * 4;
  float4 s = {0.f, 0.f, 0.f, 0.f};
  #pragma unroll
  for (int w = 0; w < 4; ++w) {
    const float4 v = *(const float4*)&sAcc[w][c];
    s.x += v.x; s.y += v.y; s.z += v.z; s.w += v.w;
  }
  *(float4*)&partial[(size_t)blockIdx.x * 1024 + c] = s;
}

// k3: out[c] = sum_j partial[j][c]; plain store (out needs no pre-zero).
__global__ __launch_bounds__(64) void k3_reduce(const float* __restrict__ partial,
                                                float* __restrict__ out, int nb) {
  const int c = blockIdx.x * 64 + threadIdx.x;
  float s = 0.f;
  #pragma unroll 16
  for (int j = 0; j < nb; ++j) s += partial[(size_t)j * 1024 + c];
  out[c] = s;
}

extern "C" void kernel_launch(void* const* d_in, const int* in_sizes, int n_in,
                              void* d_out, int out_size, void* d_ws, size_t ws_size,
                              hipStream_t stream) {
  const float* node  = (const float*)d_in[0];
  const int* elist   = (const int*)d_in[2];
  const void* maskp  = (const void*)d_in[3];
  const float* W1    = (const float*)d_in[4];
  const float* a1    = (const float*)d_in[5];
  float* out         = (float*)d_out;

  const int N = in_sizes[0] / 128;
  const int M = in_sizes[2] / 8;
  const int K2B_BLOCKS = 256;

  char* ws = (char*)d_ws;
  unsigned short* Wh = (unsigned short*)ws;             // N*256 B
  size_t off = (size_t)N * 256;
  float* sigma = (float*)(ws + off);  off += (size_t)N * 4;
  off = (off + 255) & ~(size_t)255;
  float* W8 = (float*)(ws + off);     off += (size_t)N * 32;
  off = (off + 255) & ~(size_t)255;
  float* partial = (float*)(ws + off); off += (size_t)K2B_BLOCKS * 1024 * 4;
  int* flag = (int*)(ws + off);

  k0_zero_detect<<<256, 256, 0, stream>>>((const uint32*)maskp, flag,
                                          (float4*)W8, N * 2);
  k1_mfma<<<784, 256, 0, stream>>>(node, W1, a1, Wh, sigma, N);
  k2a_edges<<<(M + 255) / 256, 256, 0, stream>>>(elist, maskp, sigma, flag, W8, M);
  k2b_nodes<<<K2B_BLOCKS, 256, 0, stream>>>((const uint32*)Wh, W8, partial, N);
  k3_reduce<<<16, 64, 0, stream>>>(partial, out, K2B_BLOCKS);
}